// Round 15
// baseline (599.040 us; speedup 1.0000x reference)
//
#include <hip/hip_runtime.h>
#include <hip/hip_bf16.h>
#include <math.h>

#define Hd   1024
#define Bsz  4096
#define Kc   3072      // concatenated K (3 x 1024)
#define NT   48        // K-tiles of 64
#define CHU  1024      // u16 per chunk: 16 rows x 64 k

typedef unsigned short u16;
typedef __attribute__((ext_vector_type(8))) u16 u16x8;
typedef __attribute__((ext_vector_type(4))) float f32x4;
typedef __attribute__((ext_vector_type(8))) short bf16x8;

__device__ inline u16 f2bf(float f) {
    __hip_bfloat16 h = __float2bfloat16(f);
    return *reinterpret_cast<u16*>(&h);
}

__device__ inline float sigm(float x) { return 1.0f / (1.0f + __expf(-x)); }

__device__ inline void gload16(const void* g, const void* s) {
    __builtin_amdgcn_global_load_lds(
        (const __attribute__((address_space(1))) void*)g,
        (__attribute__((address_space(3))) void*)s, 16, 0, 0);
}

#define BAR()   __builtin_amdgcn_s_barrier()
#define VMW(n)  asm volatile("s_waitcnt vmcnt(" #n ")" ::: "memory")
#define LGKM0() asm volatile("s_waitcnt lgkmcnt(0)" ::: "memory")
#define PRIO1() __builtin_amdgcn_s_setprio(1)
#define PRIO0() __builtin_amdgcn_s_setprio(0)

// Blocked operand layout (A and B identical): chunk(rowblk16, ktile64):
//   base = (rowblk*48 + kt)*1024;  inner: [(g = k%64/8)*16 + row%16]*8 + k%8
// Fragment read: chunkbase + ((ks*4+fq)*16+fr)*16B -> lane*16B within a
// contiguous 1KB span -> zero bank conflicts (R11/R12-verified).

// ---------------------------------------------------------------------------
// prep_A: A_cat bf16 blocked; row m' = 4*r + gate <- src row gate*1024+r.
// LDS-staged so global writes are contiguous 2KB chunks.
// ---------------------------------------------------------------------------
__global__ __launch_bounds__(256) void prep_A(const float* __restrict__ U11,
                                              const float* __restrict__ U21,
                                              const float* __restrict__ W01,
                                              u16* __restrict__ Ab,
                                              float* __restrict__ out) {
    __shared__ u16 lds[8 * 1032];
    if (blockIdx.x == 0 && blockIdx.y == 0) {
        float* outz = out + (size_t)2 * Hd * Bsz;
        for (int i = threadIdx.x; i < Bsz; i += 256) outz[i] = 0.0f;
    }
    const int mb = blockIdx.x, kb = blockIdx.y;   // mb<256, kb<6
    const int t = threadIdx.x;
    const int r16 = t >> 4, j = t & 15;
    const int row = mb * 16 + r16, gate = row & 3, r = row >> 2;
    const int sel = kb >> 1;
    const int k0 = (kb & 1) * 512 + j * 32;
    const float* src = (sel == 0) ? W01 : ((sel == 1) ? U21 : U11);
    const float4* p = reinterpret_cast<const float4*>(
        src + ((size_t)(gate * Hd + r)) * Hd + k0);
#pragma unroll
    for (int g2 = 0; g2 < 4; ++g2) {
        float4 v0 = p[g2 * 2], v1 = p[g2 * 2 + 1];
        u16x8 o;
        o[0] = f2bf(v0.x); o[1] = f2bf(v0.y); o[2] = f2bf(v0.z); o[3] = f2bf(v0.w);
        o[4] = f2bf(v1.x); o[5] = f2bf(v1.y); o[6] = f2bf(v1.z); o[7] = f2bf(v1.w);
        *reinterpret_cast<u16x8*>(
            &lds[(j >> 1) * 1032 + (((j & 1) * 4 + g2) * 16 + r16) * 8]) = o;
    }
    __syncthreads();
    const int c = t >> 5, jj = t & 31;
    u16* gdst = Ab + ((size_t)(mb * NT + kb * 8 + c)) * CHU;
#pragma unroll
    for (int i = 0; i < 4; ++i)
        *reinterpret_cast<u16x8*>(gdst + (i * 32 + jj) * 8) =
            *reinterpret_cast<const u16x8*>(&lds[c * 1032 + (i * 32 + jj) * 8]);
}

// ---------------------------------------------------------------------------
// prep_B: B_cat bf16 blocked (transpose + per-column z gating), contiguous
// chunk writes. Fused z-row partials via atomicAdd.
// ---------------------------------------------------------------------------
__global__ __launch_bounds__(256) void prep_B(const float* __restrict__ hb,
                                              const float* __restrict__ ht,
                                              const float* __restrict__ hh,
                                              const float* __restrict__ z,
                                              const float* __restrict__ zb,
                                              const float* __restrict__ U11,
                                              const float* __restrict__ U21,
                                              const float* __restrict__ W01,
                                              u16* __restrict__ Bb,
                                              float* __restrict__ out) {
    __shared__ float tile[64][33];
    __shared__ float red[8][32];
    const int n0 = blockIdx.x * 32;
    const int kg0 = blockIdx.y * 64;
    const int sel = kg0 >> 10;
    const int k0 = kg0 & 1023;
    const float* src = (sel == 0) ? hb : ((sel == 1) ? ht : hh);
    const float* wsrc = (sel == 0) ? W01 : ((sel == 1) ? U21 : U11);
    const int t = threadIdx.x, tx = t & 31, ty = t >> 5;
#pragma unroll
    for (int j = 0; j < 8; ++j) {
        int kk = ty * 8 + j;
        tile[kk][tx] = src[(size_t)(k0 + kk) * Bsz + n0 + tx];
    }
    __syncthreads();
    {   // blocked bf16 write-out: 2 chunks (16 cols x 64 k each)
        const int c = t >> 7, l = t & 127, g = l >> 4, n16 = l & 15;
        const int nl = c * 16 + n16;
        const int n = n0 + nl;
        const float s = (sel == 0) ? 1.0f : ((sel == 1) ? z[n] : zb[n]);
        u16x8 o;
#pragma unroll
        for (int e = 0; e < 8; ++e) o[e] = f2bf(tile[g * 8 + e][nl] * s);
        const int nb = (n0 >> 4) + c, kt = kg0 >> 6;
        *reinterpret_cast<u16x8*>(Bb + ((size_t)(nb * NT + kt)) * CHU +
                                  (g * 16 + n16) * 8) = o;
    }
    {   // fused z-row partial
        int col = t & 31, seg = t >> 5;
        const float* w = wsrc + (size_t)4096 * 1024 + k0 + seg * 8;
        float p = 0.0f;
#pragma unroll
        for (int j = 0; j < 8; ++j) p += w[j] * tile[seg * 8 + j][col];
        red[seg][col] = p;
        __syncthreads();
        if (seg == 0) {
            float tot = 0.0f;
#pragma unroll
            for (int q = 0; q < 8; ++q) tot += red[q][col];
            int n = n0 + col;
            float sca = (sel == 0) ? 1.0f : ((sel == 1) ? z[n] : zb[n]);
            atomicAdd(out + (size_t)2 * Hd * Bsz + n, tot * sca);
        }
    }
}

// ---------------------------------------------------------------------------
// gemm_fused: 256x256, BK=64, 8 waves (2M x 4N, per-wave 128x64), m201-style
// 8-phase engine over 2 K-tiles: fixed parity buffers, reads 16/8/0/0 per
// phase with LGKM0 fences (cross-wave WAR safety), stages 0/2/4/2 into DEAD
// regions of the compute buffer, ONE whole-tile VMW(8) guard per 4 phases
// (guarded loads 4-7 phases old), never drains mid-loop. Blocked chunk LDS:
// 0 bank conflicts. Fused LSTM epilogue; bm==0 blocks finalize z-row.
// ---------------------------------------------------------------------------
__global__ __launch_bounds__(512, 2) void gemm_fused(
    const u16* __restrict__ A, const u16* __restrict__ Bm,
    const float* __restrict__ c_in, const float* __restrict__ h_in,
    const float* __restrict__ z, const float* __restrict__ zb,
    const float* __restrict__ bias, float* __restrict__ out) {
    extern __shared__ __align__(16) u16 smem[];
    u16* const As = smem;             // [2 parity][2 half][8 chunk][1024] 64 KB
    u16* const Bs = smem + 32768;     // same, 64 KB

    const int t = threadIdx.x;
    const int w = t >> 6, l = t & 63;
    const int wm = w >> 2, wn = w & 3;
    const int fr = l & 15, fq = l >> 4;

    const int orig = blockIdx.x;                  // 256 wgs, bijective XCD swizzle
    const int wg = ((orig & 7) << 5) | (orig >> 3);
    const int bm = wg >> 4, bn = wg & 15;

    f32x4 acc[8][4];
#pragma unroll
    for (int i = 0; i < 8; ++i)
#pragma unroll
        for (int j = 0; j < 4; ++j) acc[i][j] = (f32x4){0.f, 0.f, 0.f, 0.f};

    const int wi = t >> 7, li = t & 127;          // staging sub-index
    auto stA = [&](int pt, int half, int kt) {    // 2 issues = 8 chunks (16 KB)
#pragma unroll
        for (int i = 0; i < 2; ++i) {
            int ci = i * 4 + wi;
            int rb = bm * 16 + half * 8 + ci;
            gload16(A + ((size_t)(rb * NT + kt)) * CHU + li * 8,
                    As + ((pt * 2 + half) * 8 + ci) * 1024 + li * 8);
        }
    };
    auto stB = [&](int pt, int half, int kt) {
#pragma unroll
        for (int i = 0; i < 2; ++i) {
            int ci = i * 4 + wi;
            int nb = bn * 16 + half * 8 + ci;
            gload16(Bm + ((size_t)(nb * NT + kt)) * CHU + li * 8,
                    Bs + ((pt * 2 + half) * 8 + ci) * 1024 + li * 8);
        }
    };

    auto rdA = [&](int pt, int chunk, int ks) -> bf16x8 {
        return *reinterpret_cast<const bf16x8*>(
            As + ((pt * 2 + wm) * 8 + chunk) * 1024 + ((ks * 4 + fq) * 16 + fr) * 8);
    };
    auto rdB = [&](int pt, int ni, int ks) -> bf16x8 {
        return *reinterpret_cast<const bf16x8*>(
            Bs + ((pt * 2 + (wn >> 1)) * 8 + (wn & 1) * 4 + ni) * 1024 +
            ((ks * 4 + fq) * 16 + fr) * 8);
    };

    bf16x8 aLo[4][2], aHi[4][2], bF[4][2];

#define MF16(MI0, AARR, KS)                                                   \
    PRIO1();                                                                  \
    _Pragma("unroll")                                                         \
    for (int mi = 0; mi < 4; ++mi)                                            \
        _Pragma("unroll")                                                     \
        for (int ni = 0; ni < 4; ++ni)                                        \
            acc[(MI0) + mi][ni] = __builtin_amdgcn_mfma_f32_16x16x32_bf16(    \
                AARR[mi][KS], bF[ni][KS], acc[(MI0) + mi][ni], 0, 0, 0);      \
    PRIO0()

    // 4-phase group: compute tile in buf pt; stage tile ktn (if >=0) into
    // the dead regions of buf pt. gd: 8 = steady guard, 0 = tail, -1 = none.
    auto group = [&](int pt, int ktn, int gd) {
        // ---- ph a: reads A-lo(8) + B(8); LGKM0 (regs landed -> regions
        //            dead before any wave stages); MFMA (mi0-3, ks0)
#pragma unroll
        for (int mi = 0; mi < 4; ++mi) {
            aLo[mi][0] = rdA(pt, mi, 0); aLo[mi][1] = rdA(pt, mi, 1);
        }
#pragma unroll
        for (int ni = 0; ni < 4; ++ni) {
            bF[ni][0] = rdB(pt, ni, 0); bF[ni][1] = rdB(pt, ni, 1);
        }
        LGKM0();
        BAR();
        MF16(0, aLo, 0);
        BAR();
        // ---- ph b: reads A-hi(8); LGKM0; stage B-half0[ktn]; MFMA (ks1)
#pragma unroll
        for (int mi = 0; mi < 4; ++mi) {
            aHi[mi][0] = rdA(pt, 4 + mi, 0); aHi[mi][1] = rdA(pt, 4 + mi, 1);
        }
        LGKM0();
        if (ktn >= 0) stB(pt, 0, ktn);
        BAR();
        MF16(0, aLo, 1);
        BAR();
        // ---- ph c: stage A-half0 + B-half1[ktn]; MFMA (mi4-7, ks0)
        if (ktn >= 0) { stA(pt, 0, ktn); stB(pt, 1, ktn); }
        BAR();
        MF16(4, aHi, 0);
        BAR();
        // ---- ph d: stage A-half1[ktn]; whole-tile guard; MFMA (mi4-7, ks1)
        if (ktn >= 0) stA(pt, 1, ktn);
        if (gd == 8) { VMW(8); } else if (gd == 0) { VMW(0); }
        BAR();
        MF16(4, aHi, 1);
        BAR();
    };

    // prologue: stage T0 (buf0) and T1 (buf1); T0 complete before first read
    stA(0, 0, 0); stB(0, 0, 0); stA(0, 1, 0); stB(0, 1, 0);
    stA(1, 0, 1); stB(1, 0, 1); stA(1, 1, 1); stB(1, 1, 1);
    VMW(8); BAR();

    for (int it = 0; it < NT / 2; ++it) {
        const int T0 = 2 * it;
        if (it < NT / 2 - 1) {
            group(0, T0 + 2, 8);   // guard retires T1's loads (4-7 ph old)
            group(1, T0 + 3, 8);   // guard retires T0+2's loads
        } else {
            group(0, -1, 0);       // VMW(0): T47 fully landed
            group(1, -1, -1);      // nothing outstanding
        }
    }

    // fused LSTM epilogue: acc[mi][ni] regs j = gate j of unit u, col n
    float zc[4], zbv[4];
#pragma unroll
    for (int ni = 0; ni < 4; ++ni) {
        int n = bn * 256 + wn * 64 + ni * 16 + fr;
        zc[ni] = z[n]; zbv[ni] = zb[n];
    }
#pragma unroll
    for (int mi = 0; mi < 8; ++mi) {
        const int u = bm * 64 + wm * 32 + mi * 4 + fq;
        const float b0 = bias[u], b1 = bias[Hd + u];
        const float b2 = bias[2 * Hd + u], b3 = bias[3 * Hd + u];
        const float* crow = c_in + (size_t)u * Bsz;
        const float* hrow = h_in + (size_t)u * Bsz;
        float* hout = out + (size_t)u * Bsz;
        float* cout = out + (size_t)Hd * Bsz + (size_t)u * Bsz;
#pragma unroll
        for (int ni = 0; ni < 4; ++ni) {
            const int n = bn * 256 + wn * 64 + ni * 16 + fr;
            f32x4 a = acc[mi][ni];
            float co = crow[n], ho = hrow[n];
            float fg = sigm(a[0] + b0);
            float ig = sigm(a[1] + b1);
            float og = sigm(a[2] + b2);
            float gg = tanhf(a[3] + b3);
            float i_g = ig * gg;
            float nz = 1.0f - zc[ni], nzb = 1.0f - zbv[ni];
            float cn = zc[ni] * i_g + nz * nzb * co + nz * zbv[ni] * (fg * co + i_g);
            float tc2 = tanhf(cn);
            float hn = zc[ni] * og * tc2 + nz * nzb * ho + nz * zbv[ni] * og * tc2;
            hout[n] = hn; cout[n] = cn;
        }
    }

    // z-row finalize (16 blocks with bm==0 cover all 4096 columns)
    if (bm == 0 && t < 256) {
        float* outz = out + (size_t)2 * Hd * Bsz;
        int n = bn * 256 + t;
        float s = outz[n] + bias[4096];
        float zh = (s + 1.0f) * 0.5f;
        zh = fminf(fmaxf(zh, 0.0f), 1.0f);
        outz[n] = (zh > 0.5f) ? 1.0f : 0.0f;
    }
#undef MF16
}

extern "C" void kernel_launch(void* const* d_in, const int* in_sizes, int n_in,
                              void* d_out, int out_size, void* d_ws, size_t ws_size,
                              hipStream_t stream) {
    (void)in_sizes; (void)n_in; (void)out_size; (void)ws_size;
    const float* c    = (const float*)d_in[0];
    const float* hb   = (const float*)d_in[1];
    const float* h    = (const float*)d_in[2];
    const float* ht   = (const float*)d_in[3];
    const float* z    = (const float*)d_in[4];
    const float* zb   = (const float*)d_in[5];
    const float* U11  = (const float*)d_in[6];
    const float* U21  = (const float*)d_in[7];
    const float* W01  = (const float*)d_in[8];
    const float* bias = (const float*)d_in[9];
    float* out = (float*)d_out;

    u16* Ab = (u16*)d_ws;                          // 256*48*1024*2B = 25.2 MB
    u16* Bb = Ab + (size_t)256 * NT * CHU;         // 25.2 MB

    hipFuncSetAttribute(reinterpret_cast<const void*>(gemm_fused),
                        hipFuncAttributeMaxDynamicSharedMemorySize, 131072);

    prep_A<<<dim3(256, 6), 256, 0, stream>>>(U11, U21, W01, Ab, out);
    prep_B<<<dim3(128, 48), 256, 0, stream>>>(hb, ht, h, z, zb, U11, U21, W01, Bb, out);
    gemm_fused<<<256, 512, 131072, stream>>>(Ab, Bb, c, h, z, zb, bias, out);
}